// Round 6
// baseline (820.893 us; speedup 1.0000x reference)
//
#include <hip/hip_runtime.h>
#include <math.h>

#define DI 1536
#define DM 768
#define NSTATE 16
#define DTRANK 48
#define LSEQ 1024
#define NBATCH 2
#define MROWS (NBATCH*LSEQ)   // 2048
#define NXR 3072              // 2*DI
#define NCHUNK 64
#define CLEN 16
#define SCB 128               // scan channels per block
#define DMP 16                // delta rows per block
#define NBLK_SCAN (12*NCHUNK*NBATCH)   // 1536

typedef __attribute__((ext_vector_type(4))) float f32x4;
typedef __attribute__((ext_vector_type(8))) short s16x8;
typedef __attribute__((ext_vector_type(4))) unsigned int u32x4;

__device__ __forceinline__ unsigned short f2bf(float f) {
  unsigned int x = __builtin_bit_cast(unsigned int, f);
  return (unsigned short)((x + 0x7fffu + ((x >> 16) & 1u)) >> 16);
}

__device__ __forceinline__ void gload_lds16(const void* g, void* l) {
  __builtin_amdgcn_global_load_lds(
      (const __attribute__((address_space(1))) void*)g,
      (__attribute__((address_space(3))) void*)l, 16, 0, 0);
}

// ---------------- merged prep: convert x + transpose W_in/W_out/W_x ----------------
// sections: [0,768) convert | [768,3072) W_in | [3072,4224) W_out | [4224,4368) W_x
__global__ __launch_bounds__(256) void prep_kernel(
    const float* __restrict__ x, const float* __restrict__ W_in,
    const float* __restrict__ W_out, const float* __restrict__ W_x,
    unsigned short* __restrict__ x_bf, unsigned short* __restrict__ WinT,
    unsigned short* __restrict__ WoutT, unsigned short* __restrict__ WxT)
{
  __shared__ float t[32][33];
  const int bid = blockIdx.x;
  const int tid = threadIdx.x;
  if (bid < 768) {                       // x -> x_bf (8 elems/thread)
    long i = ((long)bid * 256 + tid) * 8;
    f32x4 v0 = *(const f32x4*)&x[i];
    f32x4 v1 = *(const f32x4*)&x[i + 4];
    unsigned short o[8];
    #pragma unroll
    for (int j = 0; j < 4; ++j) { o[j] = f2bf(v0[j]); o[4 + j] = f2bf(v1[j]); }
    *(u32x4*)&x_bf[i] = *(u32x4*)o;
    return;
  }
  const float* in; unsigned short* out; int R, C, bx, by; bool guard = false;
  if (bid < 3072)      { int q = bid - 768;  in = W_in;  out = WinT;  R = DM; C = NXR; bx = q % 96; by = q / 96; }
  else if (bid < 4224) { int q = bid - 3072; in = W_out; out = WoutT; R = DI; C = DM;  bx = q % 24; by = q / 24; }
  else                 { int q = bid - 4224; in = W_x;   out = WxT;   R = DI; C = 80;  bx = q % 3;  by = q / 3; guard = true; }
  int ctile = bx * 32, rtile = by * 32;
  int tx = tid & 31, ty = tid >> 5;
  #pragma unroll
  for (int i = 0; i < 4; ++i) {
    int r = ty + i * 8;
    if (!guard || (rtile + r < R && ctile + tx < C))
      t[r][tx] = in[(long)(rtile + r) * C + ctile + tx];
  }
  __syncthreads();
  #pragma unroll
  for (int i = 0; i < 4; ++i) {
    int cc = ty + i * 8;
    if (!guard || (ctile + cc < C && rtile + tx < R))
      out[(long)(ctile + cc) * R + rtile + tx] = f2bf(t[tx][cc]);
  }
}

// ---------------- bf16 MFMA GEMM: C[M,N] = A[M,K] @ BT[N,K]^T ----------------
template<int FM, int FN>
__global__ __launch_bounds__(256) void gemm_bf16(
    const unsigned short* __restrict__ A,
    const unsigned short* __restrict__ BT,
    float* __restrict__ C, int M, int N, int K)
{
  constexpr int BM = 32 * FM, BN = 32 * FN;
  constexpr int TM = BM / 16, TN = BN / 16;
  __shared__ unsigned short Ap[BM * 32];
  __shared__ unsigned short Bp[BN * 32];
  const int tid = threadIdx.x;
  const int lane = tid & 63, wave = tid >> 6;
  const int wr = wave >> 1, wc = wave & 1;
  const int lg = lane >> 4, lr = lane & 15;
  const int m0 = blockIdx.y * BM, n0 = blockIdx.x * BN;
  f32x4 acc[FM][FN] = {};
  for (int k0 = 0; k0 < K; k0 += 32) {
    #pragma unroll
    for (int p = 0; p < TM / 4; ++p) {
      int tile = wave + p * 4;
      gload_lds16(&A[(long)(m0 + tile * 16 + lr) * K + k0 + lg * 8], &Ap[tile * 512]);
    }
    #pragma unroll
    for (int p = 0; p < TN / 4; ++p) {
      int tile = wave + p * 4;
      gload_lds16(&BT[(long)(n0 + tile * 16 + lr) * K + k0 + lg * 8], &Bp[tile * 512]);
    }
    __syncthreads();
    s16x8 af[FM], bfr[FN];
    #pragma unroll
    for (int m = 0; m < FM; ++m)
      af[m] = *(s16x8*)&Ap[(((wr * FM + m) * 4 + lg) * 16 + lr) * 8];
    #pragma unroll
    for (int n = 0; n < FN; ++n)
      bfr[n] = *(s16x8*)&Bp[(((wc * FN + n) * 4 + lg) * 16 + lr) * 8];
    #pragma unroll
    for (int m = 0; m < FM; ++m)
      #pragma unroll
      for (int n = 0; n < FN; ++n)
        acc[m][n] = __builtin_amdgcn_mfma_f32_16x16x32_bf16(af[m], bfr[n], acc[m][n], 0, 0, 0);
    __syncthreads();
  }
  #pragma unroll
  for (int m = 0; m < FM; ++m)
    #pragma unroll
    for (int n = 0; n < FN; ++n)
      #pragma unroll
      for (int r = 0; r < 4; ++r) {
        int row = m0 + wr * 16 * FM + m * 16 + lg * 4 + r;
        int col = n0 + wc * 16 * FN + n * 16 + lr;
        C[(long)row * N + col] = acc[m][n][r];
      }
}

// ---------------- depthwise causal conv(4) + bias + SiLU (f32 + bf16 out) ----------------
__global__ __launch_bounds__(256) void conv_silu_kernel(
    const float* __restrict__ xr,
    const float* __restrict__ conv_w,
    const float* __restrict__ conv_b,
    float* __restrict__ u,
    unsigned short* __restrict__ u_bf)
{
  int idx = blockIdx.x * 256 + threadIdx.x;
  if (idx >= MROWS * DI) return;
  int c = idx % DI;
  int bm = idx / DI;
  int t = bm % LSEQ;
  int b = bm / LSEQ;
  float w0 = conv_w[c * 4 + 0], w1 = conv_w[c * 4 + 1];
  float w2 = conv_w[c * 4 + 2], w3 = conv_w[c * 4 + 3];
  const float* xc = xr + (long)b * LSEQ * NXR + c;
  float acc = conv_b[c];
  if (t >= 3) acc = fmaf(xc[(long)(t - 3) * NXR], w0, acc);
  if (t >= 2) acc = fmaf(xc[(long)(t - 2) * NXR], w1, acc);
  if (t >= 1) acc = fmaf(xc[(long)(t - 1) * NXR], w2, acc);
  acc = fmaf(xc[(long)t * NXR], w3, acc);
  float s = acc / (1.f + __expf(-acc));
  u[idx] = s;
  u_bf[idx] = f2bf(s);
}

// ---------------- x_dbl = u @ W_x via MFMA; BM=16, 4 waves split K ----------------
__global__ __launch_bounds__(256) void xdbl_mfma(
    const unsigned short* __restrict__ u_bf,
    const unsigned short* __restrict__ WxT,
    float* __restrict__ xdbl)
{
  const int tid = threadIdx.x;
  const int lane = tid & 63, wave = tid >> 6;
  const int lg = lane >> 4, lr = lane & 15;
  const int m0 = blockIdx.x * 16;
  f32x4 acc[5] = {};
  const int kbase = wave * (DI / 4);
  #pragma unroll
  for (int kk = 0; kk < DI / 4; kk += 32) {
    int k0 = kbase + kk;
    s16x8 af = *(const s16x8*)&u_bf[(long)(m0 + lr) * DI + k0 + lg * 8];
    #pragma unroll
    for (int n = 0; n < 5; ++n) {
      s16x8 bfr = *(const s16x8*)&WxT[(long)(n * 16 + lr) * DI + k0 + lg * 8];
      acc[n] = __builtin_amdgcn_mfma_f32_16x16x32_bf16(af, bfr, acc[n], 0, 0, 0);
    }
  }
  __shared__ float red[4][16][80];
  #pragma unroll
  for (int n = 0; n < 5; ++n)
    #pragma unroll
    for (int r = 0; r < 4; ++r)
      red[wave][lg * 4 + r][n * 16 + lr] = acc[n][r];
  __syncthreads();
  for (int i = tid; i < 16 * 80; i += 256) {
    int row = i / 80, col = i % 80;
    float s = red[0][row][col] + red[1][row][col] + red[2][row][col] + red[3][row][col];
    xdbl[(long)(m0 + row) * 80 + col] = s;
  }
}

// ---------------- delta = softplus(xdbl[:, :48] @ W_dt + b_dt) ----------------
__global__ __launch_bounds__(256) void delta_kernel(
    const float* __restrict__ xdbl,
    const float* __restrict__ W_dt,
    const float* __restrict__ b_dt,
    float* __restrict__ delta)
{
  __shared__ float sx[DMP][DTRANK];
  const int tid = threadIdx.x;
  const int c = blockIdx.x * 256 + tid;
  const int m0 = blockIdx.y * DMP;
  for (int i = tid; i < DMP * DTRANK; i += 256) {
    int mm = i / DTRANK, r = i % DTRANK;
    sx[mm][r] = xdbl[(long)(m0 + mm) * 80 + r];
  }
  __syncthreads();
  float bias = b_dt[c];
  float acc[DMP];
  #pragma unroll
  for (int mm = 0; mm < DMP; ++mm) acc[mm] = bias;
  for (int r = 0; r < DTRANK; ++r) {
    float wv = W_dt[(long)r * DI + c];
    #pragma unroll
    for (int mm = 0; mm < DMP; ++mm)
      acc[mm] = fmaf(sx[mm][r], wv, acc[mm]);
  }
  #pragma unroll
  for (int mm = 0; mm < DMP; ++mm) {
    float v = acc[mm];
    float sp = (v > 20.f) ? v : log1pf(__expf(v));
    delta[(long)(m0 + mm) * DI + c] = sp;
  }
}

// ---------------- device-scope grid barrier (all blocks co-resident) ----------------
__device__ __forceinline__ void grid_barrier(unsigned int* bar, int slot, unsigned int target) {
  __syncthreads();
  if (threadIdx.x == 0) {
    __hip_atomic_fetch_add(&bar[slot], 1u, __ATOMIC_RELEASE, __HIP_MEMORY_SCOPE_AGENT);
    while (__hip_atomic_load(&bar[slot], __ATOMIC_ACQUIRE, __HIP_MEMORY_SCOPE_AGENT) < target)
      __builtin_amdgcn_s_sleep(1);
  }
  __syncthreads();
}

// ---------------- fused scan: local scan | chunk-prefix | replay+gate ----------------
// grid (12, NCHUNK, NBATCH) = 1536 blocks, 128 thr (2 waves).
// __launch_bounds__(128,4): VGPR<=128 -> 8 blocks/CU capacity (2048) >= 1536.
__global__ __launch_bounds__(SCB, 4) void scan_fused(
    const float* __restrict__ delta,
    const float* __restrict__ xdbl,
    const float* __restrict__ u,
    const float* __restrict__ xr,      // res at [m*NXR + DI + d]
    const float* __restrict__ A_log,
    const float* __restrict__ Dp,
    float* __restrict__ Aprod,
    float* __restrict__ Hend,
    float* __restrict__ Hstart,
    unsigned short* __restrict__ yg,
    unsigned int* __restrict__ bar)
{
  const int b = blockIdx.z, chunk = blockIdx.y;
  const int tid = threadIdx.x;
  const int d = blockIdx.x * SCB + tid;
  const long mbase = (long)b * LSEQ + chunk * CLEN;
  __shared__ float sB[CLEN][NSTATE], sC[CLEN][NSTATE];
  for (int i = tid; i < CLEN * NSTATE; i += SCB) {
    int t = i >> 4, j = i & 15;
    long mo = (mbase + t) * 80 + DTRANK + j;
    sB[t][j] = xdbl[mo];
    sC[t][j] = xdbl[mo + NSTATE];
  }
  __syncthreads();
  float a[NSTATE];
  #pragma unroll
  for (int n = 0; n < NSTATE; ++n)
    a[n] = -__expf(A_log[(long)d * NSTATE + n]);

  // ---- phase A: local scan (h0 = 0), keep dt/uu in regs for phase C ----
  float dt_[CLEN], uu_[CLEN];
  float h[NSTATE] = {};
  float Ap[NSTATE];
  #pragma unroll
  for (int n = 0; n < NSTATE; ++n) Ap[n] = 1.f;
  #pragma unroll 4
  for (int t = 0; t < CLEN; ++t) {
    long m = mbase + t;
    float dtv = delta[m * DI + d];
    float uu = u[m * DI + d];
    dt_[t] = dtv; uu_[t] = uu;
    float dtu = dtv * uu;
    #pragma unroll
    for (int n = 0; n < NSTATE; ++n) {
      float dA = __expf(dtv * a[n]);
      Ap[n] *= dA;
      h[n] = fmaf(dA, h[n], dtu * sB[t][n]);
    }
  }
  const long o = (((long)b * NCHUNK + chunk) * DI + d) * NSTATE;
  #pragma unroll
  for (int q = 0; q < 4; ++q) {
    f32x4 va = { Ap[q*4+0], Ap[q*4+1], Ap[q*4+2], Ap[q*4+3] };
    f32x4 vh = { h[q*4+0], h[q*4+1], h[q*4+2], h[q*4+3] };
    *(f32x4*)&Aprod[o + q*4] = va;
    *(f32x4*)&Hend[o + q*4] = vh;
  }
  grid_barrier(bar, 0, NBLK_SCAN);

  // ---- phase B: prefix across chunks (first 49152 threads) ----
  {
    long lb = ((long)b * gridDim.y + chunk) * gridDim.x + blockIdx.x;
    long gid = lb * SCB + tid;
    if (gid < (long)NBATCH * DI * NSTATE) {
      int bb = (int)(gid / (DI * NSTATE));
      int r = (int)(gid % (DI * NSTATE));
      long oo = (long)bb * NCHUNK * DI * NSTATE + r;
      const long stride = (long)DI * NSTATE;
      float hh = 0.f;
      #pragma unroll 4
      for (int c = 0; c < NCHUNK; ++c) {
        float Apv = Aprod[oo + c * stride];
        float Hev = Hend[oo + c * stride];
        Hstart[oo + c * stride] = hh;
        hh = fmaf(Apv, hh, Hev);
      }
    }
  }
  grid_barrier(bar, 1, NBLK_SCAN);

  // ---- phase C: replay with corrected h_start, emit gated y ----
  const float Dv = Dp[d];
  #pragma unroll
  for (int q = 0; q < 4; ++q) {
    f32x4 vh = *(const f32x4*)&Hstart[o + q*4];
    h[q*4+0] = vh[0]; h[q*4+1] = vh[1]; h[q*4+2] = vh[2]; h[q*4+3] = vh[3];
  }
  #pragma unroll 4
  for (int t = 0; t < CLEN; ++t) {
    long m = mbase + t;
    float dtv = dt_[t], uu = uu_[t];
    float rr = xr[m * NXR + DI + d];
    float dtu = dtv * uu;
    float p0 = 0.f, p1 = 0.f, p2 = 0.f, p3 = 0.f;
    #pragma unroll
    for (int q = 0; q < 4; ++q) {
      float dA0 = __expf(dtv * a[q*4+0]);
      float dA1 = __expf(dtv * a[q*4+1]);
      float dA2 = __expf(dtv * a[q*4+2]);
      float dA3 = __expf(dtv * a[q*4+3]);
      h[q*4+0] = fmaf(dA0, h[q*4+0], dtu * sB[t][q*4+0]);
      h[q*4+1] = fmaf(dA1, h[q*4+1], dtu * sB[t][q*4+1]);
      h[q*4+2] = fmaf(dA2, h[q*4+2], dtu * sB[t][q*4+2]);
      h[q*4+3] = fmaf(dA3, h[q*4+3], dtu * sB[t][q*4+3]);
    }
    #pragma unroll
    for (int n = 0; n < NSTATE; n += 4) {
      p0 = fmaf(h[n+0], sC[t][n+0], p0);
      p1 = fmaf(h[n+1], sC[t][n+1], p1);
      p2 = fmaf(h[n+2], sC[t][n+2], p2);
      p3 = fmaf(h[n+3], sC[t][n+3], p3);
    }
    float yv = (p0 + p1) + (p2 + p3) + uu * Dv;
    float gate = rr / (1.f + __expf(-rr));
    yg[m * DI + d] = f2bf(yv * gate);
  }
}

// ---------------- launch ----------------
extern "C" void kernel_launch(void* const* d_in, const int* in_sizes, int n_in,
                              void* d_out, int out_size, void* d_ws, size_t ws_size,
                              hipStream_t stream)
{
  const float* x      = (const float*)d_in[0];
  const float* W_in   = (const float*)d_in[1];
  const float* conv_w = (const float*)d_in[2];
  const float* conv_b = (const float*)d_in[3];
  const float* W_x    = (const float*)d_in[4];
  const float* W_dt   = (const float*)d_in[5];
  const float* b_dt   = (const float*)d_in[6];
  const float* A_log  = (const float*)d_in[7];
  const float* Dp     = (const float*)d_in[8];
  const float* W_out  = (const float*)d_in[9];
  float* out = (float*)d_out;

  char* p = (char*)d_ws;   // ws = 256 MiB; no aliasing needed
  float* xr     = (float*)(p + 0);            // 25165824
  float* u      = (float*)(p + 25165824);     // 12582912
  unsigned short* u_bf = (unsigned short*)(p + 37748736);   // 6291456
  float* xdbl   = (float*)(p + 44040192);     // 655360
  float* delta  = (float*)(p + 44695552);     // 12582912
  float* Aprod  = (float*)(p + 57278464);     // 12582912
  float* Hend   = (float*)(p + 69861376);     // 12582912
  float* Hstart = (float*)(p + 82444288);     // 12582912
  unsigned short* yg    = (unsigned short*)(p + 95027200);   // 6291456
  unsigned short* x_bf  = (unsigned short*)(p + 101318656);  // 3145728
  unsigned short* WinT  = (unsigned short*)(p + 104464384);  // 4718592
  unsigned short* WoutT = (unsigned short*)(p + 109182976);  // 2359296
  unsigned short* WxT   = (unsigned short*)(p + 111542272);  // 245760
  unsigned int* bar     = (unsigned int*)(p + 111788032);    // 256

  // 0. zero barrier counters (capture-safe, deterministic per call)
  hipMemsetAsync(bar, 0, 256, stream);
  // 1. merged prep: x->bf16, W_in/W_out/W_x transpose+convert
  prep_kernel<<<4368, 256, 0, stream>>>(x, W_in, W_out, W_x, x_bf, WinT, WoutT, WxT);
  // 2. x @ W_in -> xr (f32)
  gemm_bf16<4, 4><<<dim3(NXR / 128, MROWS / 128), 256, 0, stream>>>(
      x_bf, WinT, xr, MROWS, NXR, DM);
  // 3. conv + bias + silu -> u (f32) + u_bf (bf16)
  conv_silu_kernel<<<(MROWS * DI + 255) / 256, 256, 0, stream>>>(xr, conv_w, conv_b, u, u_bf);
  // 4. u @ W_x -> xdbl (MFMA)
  xdbl_mfma<<<MROWS / 16, 256, 0, stream>>>(u_bf, WxT, xdbl);
  // 5. delta
  delta_kernel<<<dim3(DI / 256, MROWS / DMP), 256, 0, stream>>>(xdbl, W_dt, b_dt, delta);
  // 6. fused 3-phase scan (device-scope grid barrier)
  scan_fused<<<dim3(DI / SCB, NCHUNK, NBATCH), SCB, 0, stream>>>(
      delta, xdbl, u, xr, A_log, Dp, Aprod, Hend, Hstart, yg, bar);
  // 7. yg @ W_out -> out
  gemm_bf16<2, 2><<<dim3(DM / 64, MROWS / 64), 256, 0, stream>>>(
      yg, WoutT, out, MROWS, DM, DI);
}

// Round 7
// 175.687 us; speedup vs baseline: 4.6725x; 4.6725x over previous
//
#include <hip/hip_runtime.h>
#include <math.h>

#define DI 1536
#define DM 768
#define NSTATE 16
#define DTRANK 48
#define LSEQ 1024
#define NBATCH 2
#define MROWS (NBATCH*LSEQ)   // 2048
#define NXR 3072              // 2*DI
#define NCHUNK 64
#define CLEN 16
#define SCB 128               // scan channels per block

typedef __attribute__((ext_vector_type(4))) float f32x4;
typedef __attribute__((ext_vector_type(8))) short s16x8;
typedef __attribute__((ext_vector_type(4))) unsigned int u32x4;

__device__ __forceinline__ unsigned short f2bf(float f) {
  unsigned int x = __builtin_bit_cast(unsigned int, f);
  return (unsigned short)((x + 0x7fffu + ((x >> 16) & 1u)) >> 16);
}

__device__ __forceinline__ void gload_lds16(const void* g, void* l) {
  __builtin_amdgcn_global_load_lds(
      (const __attribute__((address_space(1))) void*)g,
      (__attribute__((address_space(3))) void*)l, 16, 0, 0);
}

// ---------------- merged prep: convert x + transpose W_in/W_out/W_x ----------------
// sections: [0,768) convert | [768,3072) W_in | [3072,4224) W_out | [4224,4368) W_x
__global__ __launch_bounds__(256) void prep_kernel(
    const float* __restrict__ x, const float* __restrict__ W_in,
    const float* __restrict__ W_out, const float* __restrict__ W_x,
    unsigned short* __restrict__ x_bf, unsigned short* __restrict__ WinT,
    unsigned short* __restrict__ WoutT, unsigned short* __restrict__ WxT)
{
  __shared__ float t[32][33];
  const int bid = blockIdx.x;
  const int tid = threadIdx.x;
  if (bid < 768) {                       // x -> x_bf (8 elems/thread)
    long i = ((long)bid * 256 + tid) * 8;
    f32x4 v0 = *(const f32x4*)&x[i];
    f32x4 v1 = *(const f32x4*)&x[i + 4];
    unsigned short o[8];
    #pragma unroll
    for (int j = 0; j < 4; ++j) { o[j] = f2bf(v0[j]); o[4 + j] = f2bf(v1[j]); }
    *(u32x4*)&x_bf[i] = *(u32x4*)o;
    return;
  }
  const float* in; unsigned short* out; int R, C, bx, by; bool guard = false;
  if (bid < 3072)      { int q = bid - 768;  in = W_in;  out = WinT;  R = DM; C = NXR; bx = q % 96; by = q / 96; }
  else if (bid < 4224) { int q = bid - 3072; in = W_out; out = WoutT; R = DI; C = DM;  bx = q % 24; by = q / 24; }
  else                 { int q = bid - 4224; in = W_x;   out = WxT;   R = DI; C = 80;  bx = q % 3;  by = q / 3; guard = true; }
  int ctile = bx * 32, rtile = by * 32;
  int tx = tid & 31, ty = tid >> 5;
  #pragma unroll
  for (int i = 0; i < 4; ++i) {
    int r = ty + i * 8;
    if (!guard || (rtile + r < R && ctile + tx < C))
      t[r][tx] = in[(long)(rtile + r) * C + ctile + tx];
  }
  __syncthreads();
  #pragma unroll
  for (int i = 0; i < 4; ++i) {
    int cc = ty + i * 8;
    if (!guard || (ctile + cc < C && rtile + tx < R))
      out[(long)(ctile + cc) * R + rtile + tx] = f2bf(t[tx][cc]);
  }
}

// ---------------- bf16 MFMA GEMM: C[M,N] = A[M,K] @ BT[N,K]^T ----------------
template<int FM, int FN>
__global__ __launch_bounds__(256) void gemm_bf16(
    const unsigned short* __restrict__ A,
    const unsigned short* __restrict__ BT,
    float* __restrict__ C, int M, int N, int K)
{
  constexpr int BM = 32 * FM, BN = 32 * FN;
  constexpr int TM = BM / 16, TN = BN / 16;
  __shared__ unsigned short Ap[BM * 32];
  __shared__ unsigned short Bp[BN * 32];
  const int tid = threadIdx.x;
  const int lane = tid & 63, wave = tid >> 6;
  const int wr = wave >> 1, wc = wave & 1;
  const int lg = lane >> 4, lr = lane & 15;
  const int m0 = blockIdx.y * BM, n0 = blockIdx.x * BN;
  f32x4 acc[FM][FN] = {};
  for (int k0 = 0; k0 < K; k0 += 32) {
    #pragma unroll
    for (int p = 0; p < TM / 4; ++p) {
      int tile = wave + p * 4;
      gload_lds16(&A[(long)(m0 + tile * 16 + lr) * K + k0 + lg * 8], &Ap[tile * 512]);
    }
    #pragma unroll
    for (int p = 0; p < TN / 4; ++p) {
      int tile = wave + p * 4;
      gload_lds16(&BT[(long)(n0 + tile * 16 + lr) * K + k0 + lg * 8], &Bp[tile * 512]);
    }
    __syncthreads();
    s16x8 af[FM], bfr[FN];
    #pragma unroll
    for (int m = 0; m < FM; ++m)
      af[m] = *(s16x8*)&Ap[(((wr * FM + m) * 4 + lg) * 16 + lr) * 8];
    #pragma unroll
    for (int n = 0; n < FN; ++n)
      bfr[n] = *(s16x8*)&Bp[(((wc * FN + n) * 4 + lg) * 16 + lr) * 8];
    #pragma unroll
    for (int m = 0; m < FM; ++m)
      #pragma unroll
      for (int n = 0; n < FN; ++n)
        acc[m][n] = __builtin_amdgcn_mfma_f32_16x16x32_bf16(af[m], bfr[n], acc[m][n], 0, 0, 0);
    __syncthreads();
  }
  #pragma unroll
  for (int m = 0; m < FM; ++m)
    #pragma unroll
    for (int n = 0; n < FN; ++n)
      #pragma unroll
      for (int r = 0; r < 4; ++r) {
        int row = m0 + wr * 16 * FM + m * 16 + lg * 4 + r;
        int col = n0 + wc * 16 * FN + n * 16 + lr;
        C[(long)row * N + col] = acc[m][n][r];
      }
}

// ---------------- depthwise causal conv(4) + bias + SiLU (f32 + bf16 out) ----------------
__global__ __launch_bounds__(256) void conv_silu_kernel(
    const float* __restrict__ xr,
    const float* __restrict__ conv_w,
    const float* __restrict__ conv_b,
    float* __restrict__ u,
    unsigned short* __restrict__ u_bf)
{
  int idx = blockIdx.x * 256 + threadIdx.x;
  if (idx >= MROWS * DI) return;
  int c = idx % DI;
  int bm = idx / DI;
  int t = bm % LSEQ;
  int b = bm / LSEQ;
  float w0 = conv_w[c * 4 + 0], w1 = conv_w[c * 4 + 1];
  float w2 = conv_w[c * 4 + 2], w3 = conv_w[c * 4 + 3];
  const float* xc = xr + (long)b * LSEQ * NXR + c;
  float acc = conv_b[c];
  if (t >= 3) acc = fmaf(xc[(long)(t - 3) * NXR], w0, acc);
  if (t >= 2) acc = fmaf(xc[(long)(t - 2) * NXR], w1, acc);
  if (t >= 1) acc = fmaf(xc[(long)(t - 1) * NXR], w2, acc);
  acc = fmaf(xc[(long)t * NXR], w3, acc);
  float s = acc / (1.f + __expf(-acc));
  u[idx] = s;
  u_bf[idx] = f2bf(s);
}

// ---------------- x_dbl = u @ W_x via MFMA; BM=16, 4 waves split K ----------------
__global__ __launch_bounds__(256) void xdbl_mfma(
    const unsigned short* __restrict__ u_bf,
    const unsigned short* __restrict__ WxT,
    float* __restrict__ xdbl)
{
  const int tid = threadIdx.x;
  const int lane = tid & 63, wave = tid >> 6;
  const int lg = lane >> 4, lr = lane & 15;
  const int m0 = blockIdx.x * 16;
  f32x4 acc[5] = {};
  const int kbase = wave * (DI / 4);
  #pragma unroll
  for (int kk = 0; kk < DI / 4; kk += 32) {
    int k0 = kbase + kk;
    s16x8 af = *(const s16x8*)&u_bf[(long)(m0 + lr) * DI + k0 + lg * 8];
    #pragma unroll
    for (int n = 0; n < 5; ++n) {
      s16x8 bfr = *(const s16x8*)&WxT[(long)(n * 16 + lr) * DI + k0 + lg * 8];
      acc[n] = __builtin_amdgcn_mfma_f32_16x16x32_bf16(af, bfr, acc[n], 0, 0, 0);
    }
  }
  __shared__ float red[4][16][80];
  #pragma unroll
  for (int n = 0; n < 5; ++n)
    #pragma unroll
    for (int r = 0; r < 4; ++r)
      red[wave][lg * 4 + r][n * 16 + lr] = acc[n][r];
  __syncthreads();
  for (int i = tid; i < 16 * 80; i += 256) {
    int row = i / 80, col = i % 80;
    float s = red[0][row][col] + red[1][row][col] + red[2][row][col] + red[3][row][col];
    xdbl[(long)(m0 + row) * 80 + col] = s;
  }
}

// ---------------- inline delta: softplus(sX[t][0:48] . wdt + b) ----------------
__device__ __forceinline__ float compute_dt(const float* sxt, const float* wdt, float bdt) {
  float a0 = bdt, a1 = 0.f, a2 = 0.f, a3 = 0.f;
  #pragma unroll
  for (int r = 0; r < DTRANK; r += 4) {
    a0 = fmaf(sxt[r + 0], wdt[r + 0], a0);
    a1 = fmaf(sxt[r + 1], wdt[r + 1], a1);
    a2 = fmaf(sxt[r + 2], wdt[r + 2], a2);
    a3 = fmaf(sxt[r + 3], wdt[r + 3], a3);
  }
  float v = (a0 + a1) + (a2 + a3);
  return (v > 20.f) ? v : log1pf(__expf(v));
}

// ---------------- scan phase 1: local scan, dt recomputed inline ----------------
// grid (DI/SCB=12, NCHUNK, NBATCH), block SCB=128
__global__ __launch_bounds__(SCB) void scan_ph1(
    const float* __restrict__ xdbl,
    const float* __restrict__ u,
    const float* __restrict__ A_log,
    const float* __restrict__ W_dt,
    const float* __restrict__ b_dt,
    float* __restrict__ Aprod,
    float* __restrict__ Hend)
{
  const int b = blockIdx.z, chunk = blockIdx.y;
  const int tid = threadIdx.x;
  const int d = blockIdx.x * SCB + tid;
  const long mbase = (long)b * LSEQ + chunk * CLEN;
  __shared__ float sX[CLEN][80];    // full xdbl rows: [0:48) dt-in, [48:64) B, [64:80) C
  for (int i = tid; i < CLEN * 80; i += SCB) {
    int t = i / 80, j = i % 80;
    sX[t][j] = xdbl[(mbase + t) * 80 + j];
  }
  __syncthreads();
  float wdt[DTRANK];
  #pragma unroll
  for (int r = 0; r < DTRANK; ++r) wdt[r] = W_dt[(long)r * DI + d];
  const float bdt = b_dt[d];
  float a[NSTATE];
  #pragma unroll
  for (int n = 0; n < NSTATE; ++n)
    a[n] = -__expf(A_log[(long)d * NSTATE + n]);
  float h[NSTATE] = {};
  float Ap[NSTATE];
  #pragma unroll
  for (int n = 0; n < NSTATE; ++n) Ap[n] = 1.f;
  for (int t = 0; t < CLEN; ++t) {
    float dtv = compute_dt(sX[t], wdt, bdt);
    float uu = u[(mbase + t) * DI + d];
    float dtu = dtv * uu;
    #pragma unroll
    for (int n = 0; n < NSTATE; ++n) {
      float dA = __expf(dtv * a[n]);
      Ap[n] *= dA;
      h[n] = fmaf(dA, h[n], dtu * sX[t][DTRANK + n]);
    }
  }
  long o = (((long)b * NCHUNK + chunk) * DI + d) * NSTATE;
  #pragma unroll
  for (int q = 0; q < 4; ++q) {
    f32x4 va = { Ap[q*4+0], Ap[q*4+1], Ap[q*4+2], Ap[q*4+3] };
    f32x4 vh = { h[q*4+0], h[q*4+1], h[q*4+2], h[q*4+3] };
    *(f32x4*)&Aprod[o + q*4] = va;
    *(f32x4*)&Hend[o + q*4] = vh;
  }
}

// ---------------- scan phase 2: propagate h across chunks ----------------
__global__ __launch_bounds__(256) void scan_ph2(
    const float* __restrict__ Aprod,
    const float* __restrict__ Hend,
    float* __restrict__ Hstart)
{
  int idx = blockIdx.x * 256 + threadIdx.x;   // [0, 2*1536*16)
  int b = idx / (DI * NSTATE);
  int r = idx % (DI * NSTATE);
  long o = (long)b * NCHUNK * DI * NSTATE + r;
  const long stride = (long)DI * NSTATE;
  float h = 0.f;
  for (int c = 0; c < NCHUNK; ++c) {
    float Ap = Aprod[o + c * stride];
    float He = Hend[o + c * stride];
    Hstart[o + c * stride] = h;
    h = fmaf(Ap, h, He);
  }
}

// ---------------- scan phase 3: replay + y + gate -> yg (bf16) ----------------
__global__ __launch_bounds__(SCB) void scan_ph3(
    const float* __restrict__ xdbl,
    const float* __restrict__ u,
    const float* __restrict__ xr,      // res at [m*NXR + DI + d]
    const float* __restrict__ A_log,
    const float* __restrict__ W_dt,
    const float* __restrict__ b_dt,
    const float* __restrict__ Dp,
    const float* __restrict__ Hstart,
    unsigned short* __restrict__ yg)
{
  const int b = blockIdx.z, chunk = blockIdx.y;
  const int tid = threadIdx.x;
  const int d = blockIdx.x * SCB + tid;
  const long mbase = (long)b * LSEQ + chunk * CLEN;
  __shared__ float sX[CLEN][80];
  for (int i = tid; i < CLEN * 80; i += SCB) {
    int t = i / 80, j = i % 80;
    sX[t][j] = xdbl[(mbase + t) * 80 + j];
  }
  __syncthreads();
  float wdt[DTRANK];
  #pragma unroll
  for (int r = 0; r < DTRANK; ++r) wdt[r] = W_dt[(long)r * DI + d];
  const float bdt = b_dt[d];
  float a[NSTATE];
  #pragma unroll
  for (int n = 0; n < NSTATE; ++n)
    a[n] = -__expf(A_log[(long)d * NSTATE + n]);
  const float Dv = Dp[d];
  long o = (((long)b * NCHUNK + chunk) * DI + d) * NSTATE;
  float h[NSTATE];
  #pragma unroll
  for (int q = 0; q < 4; ++q) {
    f32x4 vh = *(const f32x4*)&Hstart[o + q*4];
    h[q*4+0] = vh[0]; h[q*4+1] = vh[1]; h[q*4+2] = vh[2]; h[q*4+3] = vh[3];
  }
  for (int t = 0; t < CLEN; ++t) {
    long m = mbase + t;
    float dtv = compute_dt(sX[t], wdt, bdt);
    float uu = u[m * DI + d];
    float rr = xr[m * NXR + DI + d];
    float dtu = dtv * uu;
    float p0 = 0.f, p1 = 0.f, p2 = 0.f, p3 = 0.f;
    #pragma unroll
    for (int q = 0; q < 4; ++q) {
      float dA0 = __expf(dtv * a[q*4+0]);
      float dA1 = __expf(dtv * a[q*4+1]);
      float dA2 = __expf(dtv * a[q*4+2]);
      float dA3 = __expf(dtv * a[q*4+3]);
      h[q*4+0] = fmaf(dA0, h[q*4+0], dtu * sX[t][DTRANK + q*4+0]);
      h[q*4+1] = fmaf(dA1, h[q*4+1], dtu * sX[t][DTRANK + q*4+1]);
      h[q*4+2] = fmaf(dA2, h[q*4+2], dtu * sX[t][DTRANK + q*4+2]);
      h[q*4+3] = fmaf(dA3, h[q*4+3], dtu * sX[t][DTRANK + q*4+3]);
    }
    #pragma unroll
    for (int n = 0; n < NSTATE; n += 4) {
      p0 = fmaf(h[n+0], sX[t][64 + n+0], p0);
      p1 = fmaf(h[n+1], sX[t][64 + n+1], p1);
      p2 = fmaf(h[n+2], sX[t][64 + n+2], p2);
      p3 = fmaf(h[n+3], sX[t][64 + n+3], p3);
    }
    float yv = (p0 + p1) + (p2 + p3) + uu * Dv;
    float gate = rr / (1.f + __expf(-rr));
    yg[m * DI + d] = f2bf(yv * gate);
  }
}

// ---------------- launch ----------------
extern "C" void kernel_launch(void* const* d_in, const int* in_sizes, int n_in,
                              void* d_out, int out_size, void* d_ws, size_t ws_size,
                              hipStream_t stream)
{
  const float* x      = (const float*)d_in[0];
  const float* W_in   = (const float*)d_in[1];
  const float* conv_w = (const float*)d_in[2];
  const float* conv_b = (const float*)d_in[3];
  const float* W_x    = (const float*)d_in[4];
  const float* W_dt   = (const float*)d_in[5];
  const float* b_dt   = (const float*)d_in[6];
  const float* A_log  = (const float*)d_in[7];
  const float* Dp     = (const float*)d_in[8];
  const float* W_out  = (const float*)d_in[9];
  float* out = (float*)d_out;

  char* p = (char*)d_ws;   // ws = 256 MiB
  float* xr     = (float*)(p + 0);            // 25165824
  float* u      = (float*)(p + 25165824);     // 12582912
  unsigned short* u_bf = (unsigned short*)(p + 37748736);   // 6291456
  float* xdbl   = (float*)(p + 44040192);     // 655360
  float* Aprod  = (float*)(p + 44695552);     // 12582912
  float* Hend   = (float*)(p + 57278464);     // 12582912
  float* Hstart = (float*)(p + 69861376);     // 12582912
  unsigned short* yg    = (unsigned short*)(p + 82444288);   // 6291456
  unsigned short* x_bf  = (unsigned short*)(p + 88735744);   // 3145728
  unsigned short* WinT  = (unsigned short*)(p + 91881472);   // 4718592
  unsigned short* WoutT = (unsigned short*)(p + 96600064);   // 2359296
  unsigned short* WxT   = (unsigned short*)(p + 98959360);   // 245760

  // 1. merged prep: x->bf16, W_in/W_out/W_x transpose+convert
  prep_kernel<<<4368, 256, 0, stream>>>(x, W_in, W_out, W_x, x_bf, WinT, WoutT, WxT);
  // 2. x @ W_in -> xr (f32)
  gemm_bf16<4, 4><<<dim3(NXR / 128, MROWS / 128), 256, 0, stream>>>(
      x_bf, WinT, xr, MROWS, NXR, DM);
  // 3. conv + bias + silu -> u (f32) + u_bf (bf16)
  conv_silu_kernel<<<(MROWS * DI + 255) / 256, 256, 0, stream>>>(xr, conv_w, conv_b, u, u_bf);
  // 4. u @ W_x -> xdbl (MFMA)
  xdbl_mfma<<<MROWS / 16, 256, 0, stream>>>(u_bf, WxT, xdbl);
  // 5. chunked scan (delta recomputed inline in ph1/ph3)
  scan_ph1<<<dim3(DI / SCB, NCHUNK, NBATCH), SCB, 0, stream>>>(
      xdbl, u, A_log, W_dt, b_dt, Aprod, Hend);
  scan_ph2<<<(NBATCH * DI * NSTATE) / 256, 256, 0, stream>>>(Aprod, Hend, Hstart);
  scan_ph3<<<dim3(DI / SCB, NCHUNK, NBATCH), SCB, 0, stream>>>(
      xdbl, u, xr, A_log, W_dt, b_dt, Dp, Hstart, yg);
  // 6. yg @ W_out -> out
  gemm_bf16<2, 2><<<dim3(DM / 64, MROWS / 64), 256, 0, stream>>>(
      yg, WoutT, out, MROWS, DM, DI);
}

// Round 8
// 166.892 us; speedup vs baseline: 4.9187x; 1.0527x over previous
//
#include <hip/hip_runtime.h>
#include <math.h>

#define DI 1536
#define DM 768
#define NSTATE 16
#define DTRANK 48
#define LSEQ 1024
#define NBATCH 2
#define MROWS (NBATCH*LSEQ)   // 2048
#define NXR 3072              // 2*DI
#define NCHUNK 128
#define CLEN 8
#define SCB 128               // scan channels per block
#define DMP 16                // delta rows per block

typedef __attribute__((ext_vector_type(4))) float f32x4;
typedef __attribute__((ext_vector_type(8))) short s16x8;
typedef __attribute__((ext_vector_type(4))) unsigned int u32x4;

__device__ __forceinline__ unsigned short f2bf(float f) {
  unsigned int x = __builtin_bit_cast(unsigned int, f);
  return (unsigned short)((x + 0x7fffu + ((x >> 16) & 1u)) >> 16);
}

__device__ __forceinline__ void gload_lds16(const void* g, void* l) {
  __builtin_amdgcn_global_load_lds(
      (const __attribute__((address_space(1))) void*)g,
      (__attribute__((address_space(3))) void*)l, 16, 0, 0);
}

// ---------------- merged prep: convert x + transpose W_in/W_out/W_x ----------------
__global__ __launch_bounds__(256) void prep_kernel(
    const float* __restrict__ x, const float* __restrict__ W_in,
    const float* __restrict__ W_out, const float* __restrict__ W_x,
    unsigned short* __restrict__ x_bf, unsigned short* __restrict__ WinT,
    unsigned short* __restrict__ WoutT, unsigned short* __restrict__ WxT)
{
  __shared__ float t[32][33];
  const int bid = blockIdx.x;
  const int tid = threadIdx.x;
  if (bid < 768) {                       // x -> x_bf (8 elems/thread)
    long i = ((long)bid * 256 + tid) * 8;
    f32x4 v0 = *(const f32x4*)&x[i];
    f32x4 v1 = *(const f32x4*)&x[i + 4];
    unsigned short o[8];
    #pragma unroll
    for (int j = 0; j < 4; ++j) { o[j] = f2bf(v0[j]); o[4 + j] = f2bf(v1[j]); }
    *(u32x4*)&x_bf[i] = *(u32x4*)o;
    return;
  }
  const float* in; unsigned short* out; int R, C, bx, by; bool guard = false;
  if (bid < 3072)      { int q = bid - 768;  in = W_in;  out = WinT;  R = DM; C = NXR; bx = q % 96; by = q / 96; }
  else if (bid < 4224) { int q = bid - 3072; in = W_out; out = WoutT; R = DI; C = DM;  bx = q % 24; by = q / 24; }
  else                 { int q = bid - 4224; in = W_x;   out = WxT;   R = DI; C = 80;  bx = q % 3;  by = q / 3; guard = true; }
  int ctile = bx * 32, rtile = by * 32;
  int tx = tid & 31, ty = tid >> 5;
  #pragma unroll
  for (int i = 0; i < 4; ++i) {
    int r = ty + i * 8;
    if (!guard || (rtile + r < R && ctile + tx < C))
      t[r][tx] = in[(long)(rtile + r) * C + ctile + tx];
  }
  __syncthreads();
  #pragma unroll
  for (int i = 0; i < 4; ++i) {
    int cc = ty + i * 8;
    if (!guard || (ctile + cc < C && rtile + tx < R))
      out[(long)(ctile + cc) * R + rtile + tx] = f2bf(t[tx][cc]);
  }
}

// ---------------- bf16 MFMA GEMM: C[M,N] = A[M,K] @ BT[N,K]^T ----------------
template<int FM, int FN>
__global__ __launch_bounds__(256) void gemm_bf16(
    const unsigned short* __restrict__ A,
    const unsigned short* __restrict__ BT,
    float* __restrict__ C, int M, int N, int K)
{
  constexpr int BM = 32 * FM, BN = 32 * FN;
  constexpr int TM = BM / 16, TN = BN / 16;
  __shared__ unsigned short Ap[BM * 32];
  __shared__ unsigned short Bp[BN * 32];
  const int tid = threadIdx.x;
  const int lane = tid & 63, wave = tid >> 6;
  const int wr = wave >> 1, wc = wave & 1;
  const int lg = lane >> 4, lr = lane & 15;
  const int m0 = blockIdx.y * BM, n0 = blockIdx.x * BN;
  f32x4 acc[FM][FN] = {};
  for (int k0 = 0; k0 < K; k0 += 32) {
    #pragma unroll
    for (int p = 0; p < TM / 4; ++p) {
      int tile = wave + p * 4;
      gload_lds16(&A[(long)(m0 + tile * 16 + lr) * K + k0 + lg * 8], &Ap[tile * 512]);
    }
    #pragma unroll
    for (int p = 0; p < TN / 4; ++p) {
      int tile = wave + p * 4;
      gload_lds16(&BT[(long)(n0 + tile * 16 + lr) * K + k0 + lg * 8], &Bp[tile * 512]);
    }
    __syncthreads();
    s16x8 af[FM], bfr[FN];
    #pragma unroll
    for (int m = 0; m < FM; ++m)
      af[m] = *(s16x8*)&Ap[(((wr * FM + m) * 4 + lg) * 16 + lr) * 8];
    #pragma unroll
    for (int n = 0; n < FN; ++n)
      bfr[n] = *(s16x8*)&Bp[(((wc * FN + n) * 4 + lg) * 16 + lr) * 8];
    #pragma unroll
    for (int m = 0; m < FM; ++m)
      #pragma unroll
      for (int n = 0; n < FN; ++n)
        acc[m][n] = __builtin_amdgcn_mfma_f32_16x16x32_bf16(af[m], bfr[n], acc[m][n], 0, 0, 0);
    __syncthreads();
  }
  #pragma unroll
  for (int m = 0; m < FM; ++m)
    #pragma unroll
    for (int n = 0; n < FN; ++n)
      #pragma unroll
      for (int r = 0; r < 4; ++r) {
        int row = m0 + wr * 16 * FM + m * 16 + lg * 4 + r;
        int col = n0 + wc * 16 * FN + n * 16 + lr;
        C[(long)row * N + col] = acc[m][n][r];
      }
}

// ---------------- depthwise causal conv(4) + bias + SiLU (f32 + bf16 out) ----------------
__global__ __launch_bounds__(256) void conv_silu_kernel(
    const float* __restrict__ xr,
    const float* __restrict__ conv_w,
    const float* __restrict__ conv_b,
    float* __restrict__ u,
    unsigned short* __restrict__ u_bf)
{
  int idx = blockIdx.x * 256 + threadIdx.x;
  if (idx >= MROWS * DI) return;
  int c = idx % DI;
  int bm = idx / DI;
  int t = bm % LSEQ;
  int b = bm / LSEQ;
  float w0 = conv_w[c * 4 + 0], w1 = conv_w[c * 4 + 1];
  float w2 = conv_w[c * 4 + 2], w3 = conv_w[c * 4 + 3];
  const float* xc = xr + (long)b * LSEQ * NXR + c;
  float acc = conv_b[c];
  if (t >= 3) acc = fmaf(xc[(long)(t - 3) * NXR], w0, acc);
  if (t >= 2) acc = fmaf(xc[(long)(t - 2) * NXR], w1, acc);
  if (t >= 1) acc = fmaf(xc[(long)(t - 1) * NXR], w2, acc);
  acc = fmaf(xc[(long)t * NXR], w3, acc);
  float s = acc / (1.f + __expf(-acc));
  u[idx] = s;
  u_bf[idx] = f2bf(s);
}

// ---------------- x_dbl = u @ W_x via MFMA; BM=16, 4 waves split K ----------------
__global__ __launch_bounds__(256) void xdbl_mfma(
    const unsigned short* __restrict__ u_bf,
    const unsigned short* __restrict__ WxT,
    float* __restrict__ xdbl)
{
  const int tid = threadIdx.x;
  const int lane = tid & 63, wave = tid >> 6;
  const int lg = lane >> 4, lr = lane & 15;
  const int m0 = blockIdx.x * 16;
  f32x4 acc[5] = {};
  const int kbase = wave * (DI / 4);
  #pragma unroll
  for (int kk = 0; kk < DI / 4; kk += 32) {
    int k0 = kbase + kk;
    s16x8 af = *(const s16x8*)&u_bf[(long)(m0 + lr) * DI + k0 + lg * 8];
    #pragma unroll
    for (int n = 0; n < 5; ++n) {
      s16x8 bfr = *(const s16x8*)&WxT[(long)(n * 16 + lr) * DI + k0 + lg * 8];
      acc[n] = __builtin_amdgcn_mfma_f32_16x16x32_bf16(af, bfr, acc[n], 0, 0, 0);
    }
  }
  __shared__ float red[4][16][80];
  #pragma unroll
  for (int n = 0; n < 5; ++n)
    #pragma unroll
    for (int r = 0; r < 4; ++r)
      red[wave][lg * 4 + r][n * 16 + lr] = acc[n][r];
  __syncthreads();
  for (int i = tid; i < 16 * 80; i += 256) {
    int row = i / 80, col = i % 80;
    float s = red[0][row][col] + red[1][row][col] + red[2][row][col] + red[3][row][col];
    xdbl[(long)(m0 + row) * 80 + col] = s;
  }
}

// ---------------- delta = softplus(xdbl[:, :48] @ W_dt + b_dt) ----------------
// 16 m-rows per block; W_dt element read once per 16 rows.
__global__ __launch_bounds__(256) void delta_kernel(
    const float* __restrict__ xdbl,
    const float* __restrict__ W_dt,
    const float* __restrict__ b_dt,
    float* __restrict__ delta)
{
  __shared__ float sx[DMP][DTRANK];
  const int tid = threadIdx.x;
  const int c = blockIdx.x * 256 + tid;
  const int m0 = blockIdx.y * DMP;
  for (int i = tid; i < DMP * DTRANK; i += 256) {
    int mm = i / DTRANK, r = i % DTRANK;
    sx[mm][r] = xdbl[(long)(m0 + mm) * 80 + r];
  }
  __syncthreads();
  float bias = b_dt[c];
  float acc[DMP];
  #pragma unroll
  for (int mm = 0; mm < DMP; ++mm) acc[mm] = bias;
  for (int r = 0; r < DTRANK; ++r) {
    float wv = W_dt[(long)r * DI + c];
    #pragma unroll
    for (int mm = 0; mm < DMP; ++mm)
      acc[mm] = fmaf(sx[mm][r], wv, acc[mm]);
  }
  #pragma unroll
  for (int mm = 0; mm < DMP; ++mm) {
    float v = acc[mm];
    float sp = (v > 20.f) ? v : log1pf(__expf(v));
    delta[(long)(m0 + mm) * DI + c] = sp;
  }
}

// ---------------- scan phase 1: thread-per-channel, 16 states in registers ----------------
// grid (DI/SCB=12, NCHUNK=128, NBATCH), block SCB=128
__global__ __launch_bounds__(SCB) void scan_ph1(
    const float* __restrict__ delta,
    const float* __restrict__ xdbl,
    const float* __restrict__ u,
    const float* __restrict__ A_log,
    float* __restrict__ Aprod,
    float* __restrict__ Hend)
{
  const int b = blockIdx.z, chunk = blockIdx.y;
  const int tid = threadIdx.x;
  const int d = blockIdx.x * SCB + tid;
  const long mbase = (long)b * LSEQ + chunk * CLEN;
  __shared__ float sB[CLEN][NSTATE];
  for (int i = tid; i < CLEN * NSTATE; i += SCB) {
    int t = i >> 4, j = i & 15;
    sB[t][j] = xdbl[(mbase + t) * 80 + DTRANK + j];
  }
  __syncthreads();
  float a[NSTATE];
  #pragma unroll
  for (int n = 0; n < NSTATE; ++n)
    a[n] = -__expf(A_log[(long)d * NSTATE + n]);
  float h[NSTATE] = {};
  float Ap[NSTATE];
  #pragma unroll
  for (int n = 0; n < NSTATE; ++n) Ap[n] = 1.f;
  #pragma unroll
  for (int t = 0; t < CLEN; ++t) {
    long m = mbase + t;
    float dt = delta[m * DI + d];
    float uu = u[m * DI + d];
    float dtu = dt * uu;
    #pragma unroll
    for (int n = 0; n < NSTATE; ++n) {
      float dA = __expf(dt * a[n]);
      Ap[n] *= dA;
      h[n] = fmaf(dA, h[n], dtu * sB[t][n]);
    }
  }
  long o = (((long)b * NCHUNK + chunk) * DI + d) * NSTATE;
  #pragma unroll
  for (int q = 0; q < 4; ++q) {
    f32x4 va = { Ap[q*4+0], Ap[q*4+1], Ap[q*4+2], Ap[q*4+3] };
    f32x4 vh = { h[q*4+0], h[q*4+1], h[q*4+2], h[q*4+3] };
    *(f32x4*)&Aprod[o + q*4] = va;
    *(f32x4*)&Hend[o + q*4] = vh;
  }
}

// ---------------- scan phase 2: propagate h across chunks ----------------
__global__ __launch_bounds__(256) void scan_ph2(
    const float* __restrict__ Aprod,
    const float* __restrict__ Hend,
    float* __restrict__ Hstart)
{
  int idx = blockIdx.x * 256 + threadIdx.x;   // [0, 2*1536*16)
  int b = idx / (DI * NSTATE);
  int r = idx % (DI * NSTATE);
  long o = (long)b * NCHUNK * DI * NSTATE + r;
  const long stride = (long)DI * NSTATE;
  float h = 0.f;
  for (int c = 0; c < NCHUNK; ++c) {
    float Ap = Aprod[o + c * stride];
    float He = Hend[o + c * stride];
    Hstart[o + c * stride] = h;
    h = fmaf(Ap, h, He);
  }
}

// ---------------- scan phase 3: replay + y + gate -> yg (bf16) ----------------
__global__ __launch_bounds__(SCB) void scan_ph3(
    const float* __restrict__ delta,
    const float* __restrict__ xdbl,
    const float* __restrict__ u,
    const float* __restrict__ xr,      // res at [m*NXR + DI + d]
    const float* __restrict__ A_log,
    const float* __restrict__ Dp,
    const float* __restrict__ Hstart,
    unsigned short* __restrict__ yg)
{
  const int b = blockIdx.z, chunk = blockIdx.y;
  const int tid = threadIdx.x;
  const int d = blockIdx.x * SCB + tid;
  const long mbase = (long)b * LSEQ + chunk * CLEN;
  __shared__ float sB[CLEN][NSTATE], sC[CLEN][NSTATE];
  for (int i = tid; i < CLEN * NSTATE; i += SCB) {
    int t = i >> 4, j = i & 15;
    long mo = (mbase + t) * 80 + DTRANK + j;
    sB[t][j] = xdbl[mo];
    sC[t][j] = xdbl[mo + NSTATE];
  }
  __syncthreads();
  float a[NSTATE];
  #pragma unroll
  for (int n = 0; n < NSTATE; ++n)
    a[n] = -__expf(A_log[(long)d * NSTATE + n]);
  const float Dv = Dp[d];
  long o = (((long)b * NCHUNK + chunk) * DI + d) * NSTATE;
  float h[NSTATE];
  #pragma unroll
  for (int q = 0; q < 4; ++q) {
    f32x4 vh = *(const f32x4*)&Hstart[o + q*4];
    h[q*4+0] = vh[0]; h[q*4+1] = vh[1]; h[q*4+2] = vh[2]; h[q*4+3] = vh[3];
  }
  #pragma unroll
  for (int t = 0; t < CLEN; ++t) {
    long m = mbase + t;
    float dt = delta[m * DI + d];
    float uu = u[m * DI + d];
    float rr = xr[m * NXR + DI + d];
    float dtu = dt * uu;
    float p0 = 0.f, p1 = 0.f, p2 = 0.f, p3 = 0.f;
    #pragma unroll
    for (int q = 0; q < 4; ++q) {
      float dA0 = __expf(dt * a[q*4+0]);
      float dA1 = __expf(dt * a[q*4+1]);
      float dA2 = __expf(dt * a[q*4+2]);
      float dA3 = __expf(dt * a[q*4+3]);
      h[q*4+0] = fmaf(dA0, h[q*4+0], dtu * sB[t][q*4+0]);
      h[q*4+1] = fmaf(dA1, h[q*4+1], dtu * sB[t][q*4+1]);
      h[q*4+2] = fmaf(dA2, h[q*4+2], dtu * sB[t][q*4+2]);
      h[q*4+3] = fmaf(dA3, h[q*4+3], dtu * sB[t][q*4+3]);
    }
    #pragma unroll
    for (int n = 0; n < NSTATE; n += 4) {
      p0 = fmaf(h[n+0], sC[t][n+0], p0);
      p1 = fmaf(h[n+1], sC[t][n+1], p1);
      p2 = fmaf(h[n+2], sC[t][n+2], p2);
      p3 = fmaf(h[n+3], sC[t][n+3], p3);
    }
    float yv = (p0 + p1) + (p2 + p3) + uu * Dv;
    float gate = rr / (1.f + __expf(-rr));
    yg[m * DI + d] = f2bf(yv * gate);
  }
}

// ---------------- launch ----------------
extern "C" void kernel_launch(void* const* d_in, const int* in_sizes, int n_in,
                              void* d_out, int out_size, void* d_ws, size_t ws_size,
                              hipStream_t stream)
{
  const float* x      = (const float*)d_in[0];
  const float* W_in   = (const float*)d_in[1];
  const float* conv_w = (const float*)d_in[2];
  const float* conv_b = (const float*)d_in[3];
  const float* W_x    = (const float*)d_in[4];
  const float* W_dt   = (const float*)d_in[5];
  const float* b_dt   = (const float*)d_in[6];
  const float* A_log  = (const float*)d_in[7];
  const float* Dp     = (const float*)d_in[8];
  const float* W_out  = (const float*)d_in[9];
  float* out = (float*)d_out;

  char* p = (char*)d_ws;   // ws = 256 MiB
  float* xr     = (float*)(p + 0);            // 25165824
  float* u      = (float*)(p + 25165824);     // 12582912
  unsigned short* u_bf = (unsigned short*)(p + 37748736);   // 6291456
  float* xdbl   = (float*)(p + 44040192);     // 655360
  float* delta  = (float*)(p + 44695552);     // 12582912
  float* Aprod  = (float*)(p + 57278464);     // 25165824 (NCHUNK=128)
  float* Hend   = (float*)(p + 82444288);     // 25165824
  float* Hstart = (float*)(p + 107610112);    // 25165824
  unsigned short* yg    = (unsigned short*)(p + 132775936);  // 6291456
  unsigned short* x_bf  = (unsigned short*)(p + 139067392);  // 3145728
  unsigned short* WinT  = (unsigned short*)(p + 142213120);  // 4718592
  unsigned short* WoutT = (unsigned short*)(p + 146931712);  // 2359296
  unsigned short* WxT   = (unsigned short*)(p + 149291008);  // 245760

  // 1. merged prep
  prep_kernel<<<4368, 256, 0, stream>>>(x, W_in, W_out, W_x, x_bf, WinT, WoutT, WxT);
  // 2. x @ W_in -> xr (f32)
  gemm_bf16<4, 4><<<dim3(NXR / 128, MROWS / 128), 256, 0, stream>>>(
      x_bf, WinT, xr, MROWS, NXR, DM);
  // 3. conv + bias + silu -> u (f32) + u_bf (bf16)
  conv_silu_kernel<<<(MROWS * DI + 255) / 256, 256, 0, stream>>>(xr, conv_w, conv_b, u, u_bf);
  // 4. u @ W_x -> xdbl (MFMA)
  xdbl_mfma<<<MROWS / 16, 256, 0, stream>>>(u_bf, WxT, xdbl);
  // 5. delta
  delta_kernel<<<dim3(DI / 256, MROWS / DMP), 256, 0, stream>>>(xdbl, W_dt, b_dt, delta);
  // 6. chunked scan (NCHUNK=128, CLEN=8)
  scan_ph1<<<dim3(DI / SCB, NCHUNK, NBATCH), SCB, 0, stream>>>(
      delta, xdbl, u, A_log, Aprod, Hend);
  scan_ph2<<<(NBATCH * DI * NSTATE) / 256, 256, 0, stream>>>(Aprod, Hend, Hstart);
  scan_ph3<<<dim3(DI / SCB, NCHUNK, NBATCH), SCB, 0, stream>>>(
      delta, xdbl, u, xr, A_log, Dp, Hstart, yg);
  // 7. yg @ W_out -> out
  gemm_bf16<2, 2><<<dim3(DM / 64, MROWS / 64), 256, 0, stream>>>(
      yg, WoutT, out, MROWS, DM, DI);
}

// Round 9
// 160.099 us; speedup vs baseline: 5.1274x; 1.0424x over previous
//
#include <hip/hip_runtime.h>
#include <math.h>

#define DI 1536
#define DM 768
#define NSTATE 16
#define DTRANK 48
#define LSEQ 1024
#define NBATCH 2
#define MROWS (NBATCH*LSEQ)   // 2048
#define NXR 3072              // 2*DI
#define NCHUNK 128
#define CLEN 8
#define SCB 128               // scan channels per block
#define DMP 16                // delta rows per block

typedef __attribute__((ext_vector_type(4))) float f32x4;
typedef __attribute__((ext_vector_type(8))) short s16x8;
typedef __attribute__((ext_vector_type(4))) unsigned int u32x4;

__device__ __forceinline__ unsigned short f2bf(float f) {
  unsigned int x = __builtin_bit_cast(unsigned int, f);
  return (unsigned short)((x + 0x7fffu + ((x >> 16) & 1u)) >> 16);
}

__device__ __forceinline__ void gload_lds16(const void* g, void* l) {
  __builtin_amdgcn_global_load_lds(
      (const __attribute__((address_space(1))) void*)g,
      (__attribute__((address_space(3))) void*)l, 16, 0, 0);
}

// ---------------- merged prep ----------------
// [0,768) x->bf16 | [768,3072) W_in^T | [3072,4224) W_out^T | [4224,4368) W_x^T
// [4368,4416) negA[n][d] = -exp(A_log[d][n])
__global__ __launch_bounds__(256) void prep_kernel(
    const float* __restrict__ x, const float* __restrict__ W_in,
    const float* __restrict__ W_out, const float* __restrict__ W_x,
    const float* __restrict__ A_log,
    unsigned short* __restrict__ x_bf, unsigned short* __restrict__ WinT,
    unsigned short* __restrict__ WoutT, unsigned short* __restrict__ WxT,
    float* __restrict__ negA)
{
  __shared__ float t[32][33];
  const int bid = blockIdx.x;
  const int tid = threadIdx.x;
  if (bid < 768) {                       // x -> x_bf (8 elems/thread)
    long i = ((long)bid * 256 + tid) * 8;
    f32x4 v0 = *(const f32x4*)&x[i];
    f32x4 v1 = *(const f32x4*)&x[i + 4];
    unsigned short o[8];
    #pragma unroll
    for (int j = 0; j < 4; ++j) { o[j] = f2bf(v0[j]); o[4 + j] = f2bf(v1[j]); }
    *(u32x4*)&x_bf[i] = *(u32x4*)o;
    return;
  }
  int tx = tid & 31, ty = tid >> 5;
  if (bid >= 4368) {                     // A_log [DI][16] -> negA [16][DI]
    int rtile = (bid - 4368) * 32;
    #pragma unroll
    for (int i = 0; i < 4; ++i) {
      int r = ty + i * 8;
      if (tx < 16) t[r][tx] = A_log[(long)(rtile + r) * NSTATE + tx];
    }
    __syncthreads();
    #pragma unroll
    for (int i = 0; i < 2; ++i) {
      int cc = ty + i * 8;               // 0..15
      negA[(long)cc * DI + rtile + tx] = -__expf(t[tx][cc]);
    }
    return;
  }
  const float* in; unsigned short* out; int R, C, bx, by; bool guard = false;
  if (bid < 3072)      { int q = bid - 768;  in = W_in;  out = WinT;  R = DM; C = NXR; bx = q % 96; by = q / 96; }
  else if (bid < 4224) { int q = bid - 3072; in = W_out; out = WoutT; R = DI; C = DM;  bx = q % 24; by = q / 24; }
  else                 { int q = bid - 4224; in = W_x;   out = WxT;   R = DI; C = 80;  bx = q % 3;  by = q / 3; guard = true; }
  int ctile = bx * 32, rtile = by * 32;
  #pragma unroll
  for (int i = 0; i < 4; ++i) {
    int r = ty + i * 8;
    if (!guard || (rtile + r < R && ctile + tx < C))
      t[r][tx] = in[(long)(rtile + r) * C + ctile + tx];
  }
  __syncthreads();
  #pragma unroll
  for (int i = 0; i < 4; ++i) {
    int cc = ty + i * 8;
    if (!guard || (ctile + cc < C && rtile + tx < R))
      out[(long)(ctile + cc) * R + rtile + tx] = f2bf(t[tx][cc]);
  }
}

// ---------------- bf16 MFMA GEMM: C[M,N] = A[M,K] @ BT[N,K]^T ----------------
template<int FM, int FN>
__global__ __launch_bounds__(256) void gemm_bf16(
    const unsigned short* __restrict__ A,
    const unsigned short* __restrict__ BT,
    float* __restrict__ C, int M, int N, int K)
{
  constexpr int BM = 32 * FM, BN = 32 * FN;
  constexpr int TM = BM / 16, TN = BN / 16;
  __shared__ unsigned short Ap[BM * 32];
  __shared__ unsigned short Bp[BN * 32];
  const int tid = threadIdx.x;
  const int lane = tid & 63, wave = tid >> 6;
  const int wr = wave >> 1, wc = wave & 1;
  const int lg = lane >> 4, lr = lane & 15;
  const int m0 = blockIdx.y * BM, n0 = blockIdx.x * BN;
  f32x4 acc[FM][FN] = {};
  for (int k0 = 0; k0 < K; k0 += 32) {
    #pragma unroll
    for (int p = 0; p < TM / 4; ++p) {
      int tile = wave + p * 4;
      gload_lds16(&A[(long)(m0 + tile * 16 + lr) * K + k0 + lg * 8], &Ap[tile * 512]);
    }
    #pragma unroll
    for (int p = 0; p < TN / 4; ++p) {
      int tile = wave + p * 4;
      gload_lds16(&BT[(long)(n0 + tile * 16 + lr) * K + k0 + lg * 8], &Bp[tile * 512]);
    }
    __syncthreads();
    s16x8 af[FM], bfr[FN];
    #pragma unroll
    for (int m = 0; m < FM; ++m)
      af[m] = *(s16x8*)&Ap[(((wr * FM + m) * 4 + lg) * 16 + lr) * 8];
    #pragma unroll
    for (int n = 0; n < FN; ++n)
      bfr[n] = *(s16x8*)&Bp[(((wc * FN + n) * 4 + lg) * 16 + lr) * 8];
    #pragma unroll
    for (int m = 0; m < FM; ++m)
      #pragma unroll
      for (int n = 0; n < FN; ++n)
        acc[m][n] = __builtin_amdgcn_mfma_f32_16x16x32_bf16(af[m], bfr[n], acc[m][n], 0, 0, 0);
    __syncthreads();
  }
  #pragma unroll
  for (int m = 0; m < FM; ++m)
    #pragma unroll
    for (int n = 0; n < FN; ++n)
      #pragma unroll
      for (int r = 0; r < 4; ++r) {
        int row = m0 + wr * 16 * FM + m * 16 + lg * 4 + r;
        int col = n0 + wc * 16 * FN + n * 16 + lr;
        C[(long)row * N + col] = acc[m][n][r];
      }
}

// ---------------- depthwise causal conv(4) + bias + SiLU (f32 + bf16 out) ----------------
__global__ __launch_bounds__(256) void conv_silu_kernel(
    const float* __restrict__ xr,
    const float* __restrict__ conv_w,
    const float* __restrict__ conv_b,
    float* __restrict__ u,
    unsigned short* __restrict__ u_bf)
{
  int idx = blockIdx.x * 256 + threadIdx.x;
  if (idx >= MROWS * DI) return;
  int c = idx % DI;
  int bm = idx / DI;
  int t = bm % LSEQ;
  int b = bm / LSEQ;
  float w0 = conv_w[c * 4 + 0], w1 = conv_w[c * 4 + 1];
  float w2 = conv_w[c * 4 + 2], w3 = conv_w[c * 4 + 3];
  const float* xc = xr + (long)b * LSEQ * NXR + c;
  float acc = conv_b[c];
  if (t >= 3) acc = fmaf(xc[(long)(t - 3) * NXR], w0, acc);
  if (t >= 2) acc = fmaf(xc[(long)(t - 2) * NXR], w1, acc);
  if (t >= 1) acc = fmaf(xc[(long)(t - 1) * NXR], w2, acc);
  acc = fmaf(xc[(long)t * NXR], w3, acc);
  float s = acc / (1.f + __expf(-acc));
  u[idx] = s;
  u_bf[idx] = f2bf(s);
}

// ---------------- x_dbl = u @ W_x via MFMA; BM=16, 4 waves split K ----------------
__global__ __launch_bounds__(256) void xdbl_mfma(
    const unsigned short* __restrict__ u_bf,
    const unsigned short* __restrict__ WxT,
    float* __restrict__ xdbl)
{
  const int tid = threadIdx.x;
  const int lane = tid & 63, wave = tid >> 6;
  const int lg = lane >> 4, lr = lane & 15;
  const int m0 = blockIdx.x * 16;
  f32x4 acc[5] = {};
  const int kbase = wave * (DI / 4);
  #pragma unroll
  for (int kk = 0; kk < DI / 4; kk += 32) {
    int k0 = kbase + kk;
    s16x8 af = *(const s16x8*)&u_bf[(long)(m0 + lr) * DI + k0 + lg * 8];
    #pragma unroll
    for (int n = 0; n < 5; ++n) {
      s16x8 bfr = *(const s16x8*)&WxT[(long)(n * 16 + lr) * DI + k0 + lg * 8];
      acc[n] = __builtin_amdgcn_mfma_f32_16x16x32_bf16(af, bfr, acc[n], 0, 0, 0);
    }
  }
  __shared__ float red[4][16][80];
  #pragma unroll
  for (int n = 0; n < 5; ++n)
    #pragma unroll
    for (int r = 0; r < 4; ++r)
      red[wave][lg * 4 + r][n * 16 + lr] = acc[n][r];
  __syncthreads();
  for (int i = tid; i < 16 * 80; i += 256) {
    int row = i / 80, col = i % 80;
    float s = red[0][row][col] + red[1][row][col] + red[2][row][col] + red[3][row][col];
    xdbl[(long)(m0 + row) * 80 + col] = s;
  }
}

// ---------------- delta = softplus(xdbl[:, :48] @ W_dt + b_dt) ----------------
__global__ __launch_bounds__(256) void delta_kernel(
    const float* __restrict__ xdbl,
    const float* __restrict__ W_dt,
    const float* __restrict__ b_dt,
    float* __restrict__ delta)
{
  __shared__ float sx[DMP][DTRANK];
  const int tid = threadIdx.x;
  const int c = blockIdx.x * 256 + tid;
  const int m0 = blockIdx.y * DMP;
  for (int i = tid; i < DMP * DTRANK; i += 256) {
    int mm = i / DTRANK, r = i % DTRANK;
    sx[mm][r] = xdbl[(long)(m0 + mm) * 80 + r];
  }
  __syncthreads();
  float bias = b_dt[c];
  float acc[DMP];
  #pragma unroll
  for (int mm = 0; mm < DMP; ++mm) acc[mm] = bias;
  for (int r = 0; r < DTRANK; ++r) {
    float wv = W_dt[(long)r * DI + c];
    #pragma unroll
    for (int mm = 0; mm < DMP; ++mm)
      acc[mm] = fmaf(sx[mm][r], wv, acc[mm]);
  }
  #pragma unroll
  for (int mm = 0; mm < DMP; ++mm) {
    float v = acc[mm];
    float sp = (v > 20.f) ? v : log1pf(__expf(v));
    delta[(long)(m0 + mm) * DI + c] = sp;
  }
}

// ---------------- scan phase 1: n-major state, coalesced stores ----------------
// grid (DI/SCB=12, NCHUNK=128, NBATCH), block SCB=128
// state element addr: ((b*NCHUNK+chunk)*NSTATE + n)*DI + d
__global__ __launch_bounds__(SCB) void scan_ph1(
    const float* __restrict__ delta,
    const float* __restrict__ xdbl,
    const float* __restrict__ u,
    const float* __restrict__ negA,
    float* __restrict__ Aprod,
    float* __restrict__ Hend)
{
  const int b = blockIdx.z, chunk = blockIdx.y;
  const int tid = threadIdx.x;
  const int d = blockIdx.x * SCB + tid;
  const long mbase = (long)b * LSEQ + chunk * CLEN;
  __shared__ float sB[CLEN][NSTATE];
  for (int i = tid; i < CLEN * NSTATE; i += SCB) {
    int t = i >> 4, j = i & 15;
    sB[t][j] = xdbl[(mbase + t) * 80 + DTRANK + j];
  }
  __syncthreads();
  float a[NSTATE];
  #pragma unroll
  for (int n = 0; n < NSTATE; ++n)
    a[n] = negA[(long)n * DI + d];
  float h[NSTATE] = {};
  float Ap[NSTATE];
  #pragma unroll
  for (int n = 0; n < NSTATE; ++n) Ap[n] = 1.f;
  #pragma unroll
  for (int t = 0; t < CLEN; ++t) {
    long m = mbase + t;
    float dt = delta[m * DI + d];
    float uu = u[m * DI + d];
    float dtu = dt * uu;
    #pragma unroll
    for (int n = 0; n < NSTATE; ++n) {
      float dA = __expf(dt * a[n]);
      Ap[n] *= dA;
      h[n] = fmaf(dA, h[n], dtu * sB[t][n]);
    }
  }
  const long o = ((long)(b * NCHUNK + chunk) * NSTATE) * DI + d;
  #pragma unroll
  for (int n = 0; n < NSTATE; ++n) {
    Aprod[o + (long)n * DI] = Ap[n];
    Hend[o + (long)n * DI] = h[n];
  }
}

// ---------------- scan phase 2: prefix across chunks; Hend -> Hstart in place ----------------
__global__ __launch_bounds__(256) void scan_ph2(
    const float* __restrict__ Aprod,
    float* __restrict__ Hend)     // in: per-chunk h_end; out: per-chunk h_start
{
  int idx = blockIdx.x * 256 + threadIdx.x;   // [0, 2*1536*16)
  int b = idx / (DI * NSTATE);
  int r = idx % (DI * NSTATE);
  long o = (long)b * NCHUNK * DI * NSTATE + r;
  const long stride = (long)DI * NSTATE;
  float h = 0.f;
  for (int c = 0; c < NCHUNK; ++c) {
    float Ap = Aprod[o + c * stride];
    float He = Hend[o + c * stride];
    Hend[o + c * stride] = h;
    h = fmaf(Ap, h, He);
  }
}

// ---------------- scan phase 3: replay + y + gate -> yg (bf16) ----------------
__global__ __launch_bounds__(SCB) void scan_ph3(
    const float* __restrict__ delta,
    const float* __restrict__ xdbl,
    const float* __restrict__ u,
    const float* __restrict__ xr,      // res at [m*NXR + DI + d]
    const float* __restrict__ negA,
    const float* __restrict__ Dp,
    const float* __restrict__ Hstart,  // = Hend buffer after ph2
    unsigned short* __restrict__ yg)
{
  const int b = blockIdx.z, chunk = blockIdx.y;
  const int tid = threadIdx.x;
  const int d = blockIdx.x * SCB + tid;
  const long mbase = (long)b * LSEQ + chunk * CLEN;
  __shared__ float sB[CLEN][NSTATE], sC[CLEN][NSTATE];
  for (int i = tid; i < CLEN * NSTATE; i += SCB) {
    int t = i >> 4, j = i & 15;
    long mo = (mbase + t) * 80 + DTRANK + j;
    sB[t][j] = xdbl[mo];
    sC[t][j] = xdbl[mo + NSTATE];
  }
  __syncthreads();
  float a[NSTATE];
  #pragma unroll
  for (int n = 0; n < NSTATE; ++n)
    a[n] = negA[(long)n * DI + d];
  const float Dv = Dp[d];
  const long o = ((long)(b * NCHUNK + chunk) * NSTATE) * DI + d;
  float h[NSTATE];
  #pragma unroll
  for (int n = 0; n < NSTATE; ++n)
    h[n] = Hstart[o + (long)n * DI];
  #pragma unroll
  for (int t = 0; t < CLEN; ++t) {
    long m = mbase + t;
    float dt = delta[m * DI + d];
    float uu = u[m * DI + d];
    float rr = xr[m * NXR + DI + d];
    float dtu = dt * uu;
    float p0 = 0.f, p1 = 0.f, p2 = 0.f, p3 = 0.f;
    #pragma unroll
    for (int q = 0; q < 4; ++q) {
      float dA0 = __expf(dt * a[q*4+0]);
      float dA1 = __expf(dt * a[q*4+1]);
      float dA2 = __expf(dt * a[q*4+2]);
      float dA3 = __expf(dt * a[q*4+3]);
      h[q*4+0] = fmaf(dA0, h[q*4+0], dtu * sB[t][q*4+0]);
      h[q*4+1] = fmaf(dA1, h[q*4+1], dtu * sB[t][q*4+1]);
      h[q*4+2] = fmaf(dA2, h[q*4+2], dtu * sB[t][q*4+2]);
      h[q*4+3] = fmaf(dA3, h[q*4+3], dtu * sB[t][q*4+3]);
    }
    #pragma unroll
    for (int n = 0; n < NSTATE; n += 4) {
      p0 = fmaf(h[n+0], sC[t][n+0], p0);
      p1 = fmaf(h[n+1], sC[t][n+1], p1);
      p2 = fmaf(h[n+2], sC[t][n+2], p2);
      p3 = fmaf(h[n+3], sC[t][n+3], p3);
    }
    float yv = (p0 + p1) + (p2 + p3) + uu * Dv;
    float gate = rr / (1.f + __expf(-rr));
    yg[m * DI + d] = f2bf(yv * gate);
  }
}

// ---------------- launch ----------------
extern "C" void kernel_launch(void* const* d_in, const int* in_sizes, int n_in,
                              void* d_out, int out_size, void* d_ws, size_t ws_size,
                              hipStream_t stream)
{
  const float* x      = (const float*)d_in[0];
  const float* W_in   = (const float*)d_in[1];
  const float* conv_w = (const float*)d_in[2];
  const float* conv_b = (const float*)d_in[3];
  const float* W_x    = (const float*)d_in[4];
  const float* W_dt   = (const float*)d_in[5];
  const float* b_dt   = (const float*)d_in[6];
  const float* A_log  = (const float*)d_in[7];
  const float* Dp     = (const float*)d_in[8];
  const float* W_out  = (const float*)d_in[9];
  float* out = (float*)d_out;

  char* p = (char*)d_ws;   // ws = 256 MiB
  float* xr     = (float*)(p + 0);            // 25165824
  float* u      = (float*)(p + 25165824);     // 12582912
  unsigned short* u_bf = (unsigned short*)(p + 37748736);   // 6291456
  float* xdbl   = (float*)(p + 44040192);     // 655360
  float* delta  = (float*)(p + 44695552);     // 12582912
  float* Aprod  = (float*)(p + 57278464);     // 25165824 (NCHUNK=128)
  float* Hend   = (float*)(p + 82444288);     // 25165824 (Hstart after ph2)
  unsigned short* yg    = (unsigned short*)(p + 107610112); // 6291456
  unsigned short* x_bf  = (unsigned short*)(p + 113901568); // 3145728
  unsigned short* WinT  = (unsigned short*)(p + 117047296); // 4718592
  unsigned short* WoutT = (unsigned short*)(p + 121765888); // 2359296
  unsigned short* WxT   = (unsigned short*)(p + 124125184); // 245760
  float* negA   = (float*)(p + 124370944);    // 98304

  // 1. merged prep (incl. negA)
  prep_kernel<<<4416, 256, 0, stream>>>(x, W_in, W_out, W_x, A_log,
                                        x_bf, WinT, WoutT, WxT, negA);
  // 2. x @ W_in -> xr (f32)
  gemm_bf16<4, 4><<<dim3(NXR / 128, MROWS / 128), 256, 0, stream>>>(
      x_bf, WinT, xr, MROWS, NXR, DM);
  // 3. conv + bias + silu -> u (f32) + u_bf (bf16)
  conv_silu_kernel<<<(MROWS * DI + 255) / 256, 256, 0, stream>>>(xr, conv_w, conv_b, u, u_bf);
  // 4. u @ W_x -> xdbl (MFMA)
  xdbl_mfma<<<MROWS / 16, 256, 0, stream>>>(u_bf, WxT, xdbl);
  // 5. delta
  delta_kernel<<<dim3(DI / 256, MROWS / DMP), 256, 0, stream>>>(xdbl, W_dt, b_dt, delta);
  // 6. chunked scan (n-major state)
  scan_ph1<<<dim3(DI / SCB, NCHUNK, NBATCH), SCB, 0, stream>>>(
      delta, xdbl, u, negA, Aprod, Hend);
  scan_ph2<<<(NBATCH * DI * NSTATE) / 256, 256, 0, stream>>>(Aprod, Hend);
  scan_ph3<<<dim3(DI / SCB, NCHUNK, NBATCH), SCB, 0, stream>>>(
      delta, xdbl, u, xr, negA, Dp, Hend, yg);
  // 7. yg @ W_out -> out
  gemm_bf16<2, 2><<<dim3(DM / 64, MROWS / 64), 256, 0, stream>>>(
      yg, WoutT, out, MROWS, DM, DI);
}